// Round 1
// 496.086 us; speedup vs baseline: 1.0149x; 1.0149x over previous
//
#include <hip/hip_runtime.h>

// Round 3: pipelined fused kernel.
// gru_fused: LDS double-buffer (2 x 36864 B), prefetch tile t+1 issued BEFORE
// computing tile t, counted s_waitcnt vmcnt(9) + raw s_barrier (never drain to
// 0 in the main loop), XOR slot-swizzle on all ds_read_b128 (pre-swizzled
// global source, linear LDS dest per global_load_lds rules), setprio(1) around
// the MFMA cluster. convert_bf16: 2048-block grid-stride.

#define BM 128
#define BN 64
#define BK 32
#define TILE_BYTES 36864

typedef __attribute__((ext_vector_type(8))) short          bf16x8;
typedef __attribute__((ext_vector_type(8))) unsigned short u16x8;
typedef __attribute__((ext_vector_type(4))) float          f32x4;

__device__ __forceinline__ unsigned short f2bf(float f) {
    union { float f; unsigned u; } v; v.f = f;
    unsigned r = v.u + 0x7FFFu + ((v.u >> 16) & 1u);  // RNE
    return (unsigned short)(r >> 16);
}

// ---- Pass 1: fp32 -> bf16 conversion into ws (grid-stride, 2048 blocks) ----
// ws layout (elements): [0) input 16777216 | [16777216) hidden 16777216 |
//                       [33554432 + g*1048576) W_g for g=0..4
// Total vec8 units = 4,849,664.
__global__ __launch_bounds__(256) void convert_bf16(
    const float* __restrict__ in0, const float* __restrict__ in1,
    const float* __restrict__ w0, const float* __restrict__ w1,
    const float* __restrict__ w2, const float* __restrict__ w3,
    const float* __restrict__ w4, unsigned short* __restrict__ ws)
{
    const long long stride = (long long)gridDim.x * 256;
    for (long long u = (long long)blockIdx.x * 256 + threadIdx.x;
         u < 4849664LL; u += stride) {
        const long long e = u * 8;
        const float* src;
        if (e < 16777216LL) {
            src = in0 + e;
        } else if (e < 33554432LL) {
            src = in1 + (e - 16777216LL);
        } else {
            const long long t = e - 33554432LL;
            const int g = (int)(t >> 20);
            const long long within = t & 1048575LL;
            const float* w = (g == 0) ? w0 : (g == 1) ? w1 : (g == 2) ? w2 : (g == 3) ? w3 : w4;
            src = w + within;
        }
        const float4 a = *reinterpret_cast<const float4*>(src);
        const float4 b = *reinterpret_cast<const float4*>(src + 4);
        u16x8 o;
        o[0] = f2bf(a.x); o[1] = f2bf(a.y); o[2] = f2bf(a.z); o[3] = f2bf(a.w);
        o[4] = f2bf(b.x); o[5] = f2bf(b.y); o[6] = f2bf(b.z); o[7] = f2bf(b.w);
        *reinterpret_cast<u16x8*>(ws + e) = o;
    }
}

// ---- async 16B global->LDS ----
__device__ __forceinline__ void async16(const void* g, void* l) {
    __builtin_amdgcn_global_load_lds(
        (const __attribute__((address_space(1))) unsigned int*)g,
        (__attribute__((address_space(3))) unsigned int*)l, 16, 0, 0);
}

// compiler-level memory fence (no instruction) to bracket raw s_barrier so
// ds_reads cannot be hoisted above / sunk below it (rule #18/#21 hygiene)
#define CFENCE() asm volatile("" ::: "memory")

// ---- Pass 2: fused GRU, double-buffered + swizzled ----
// Per-tile LDS image (bf16, linear dest as global_load_lds requires):
//   [0, 8192)       sIn  [128 rows][64 B]   (4 x 16B slots per row)
//   [8192, 16384)   sHid [128 rows][64 B]
//   [16384, 36864)  sW[5][64 rows][64 B]
// Slot swizzle: data for logical 16B slot c of row r is stored at physical
// slot c ^ ((r>>1)&3)  (applied on the GLOBAL source at staging; involution
// applied again on the read side). Spreads the 16 lanes of each quad-group
// over all 8 slot positions per 128B bank span (2/position = free) instead of
// 2 positions (8-way conflict).
__global__ __launch_bounds__(256, 2) void gru_fused(
    const unsigned short* __restrict__ bf,   // ws: bf16 image
    const float* __restrict__ hidden,        // fp32, for epilogue z*h
    const float* __restrict__ b_ri, const float* __restrict__ b_rh,
    const float* __restrict__ b_zi, const float* __restrict__ b_ni,
    const float* __restrict__ b_nh,
    float* __restrict__ out)
{
    const int H = 1024, K = 1024;
    const int BH = 16384 * 1024;

    __shared__ __align__(16) unsigned char sBuf[2][TILE_BYTES];

    const int tid  = threadIdx.x;
    const int wave = tid >> 6;
    const int lane = tid & 63;
    const int quad = lane >> 4;
    const int l16  = lane & 15;
    const int sq   = quad ^ ((l16 >> 1) & 3);   // swizzled 16B slot for reads

    const int row0 = blockIdx.y * BM;
    const int col0 = blockIdx.x * BN;

    const unsigned short* inB  = bf;               // input  bf16 [16384][1024]
    const unsigned short* hidB = bf + 16777216;    // hidden bf16 [16384][1024]
    const unsigned short* wB   = bf + 33554432;    // W bf16 [5][1024][1024]

    // Per-slot global base pointers (k0=0, source slot pre-swizzled) + LDS offs.
    const unsigned short* srcbase[9];
    int ldsoff[9];
    #pragma unroll
    for (int j = 0; j < 9; ++j) {
        const int s = (j * 4 + wave) * 64 + lane;
        ldsoff[j] = s * 16;
        if (s < 512) {                       // input tile
            const int r = s >> 2;
            const int c = (s & 3) ^ ((r >> 1) & 3);
            srcbase[j] = inB + (long long)(row0 + r) * K + c * 8;
        } else if (s < 1024) {               // hidden tile
            const int r = (s - 512) >> 2;
            const int c = (s & 3) ^ ((r >> 1) & 3);
            srcbase[j] = hidB + (long long)(row0 + r) * K + c * 8;
        } else {                             // weight tiles
            const int t = s - 1024;
            const int g = t >> 8;
            const int tt = t & 255;
            const int n = tt >> 2;
            const int c = (tt & 3) ^ ((n >> 1) & 3);
            srcbase[j] = wB + (long long)g * 1048576 + (long long)(col0 + n) * K + c * 8;
        }
    }

    f32x4 acc[5][2][4];
    #pragma unroll
    for (int g = 0; g < 5; ++g)
        #pragma unroll
        for (int mi = 0; mi < 2; ++mi)
            #pragma unroll
            for (int ni = 0; ni < 4; ++ni)
                acc[g][mi][ni] = (f32x4){0.f, 0.f, 0.f, 0.f};

    unsigned char* b0 = &sBuf[0][0];
    unsigned char* b1 = &sBuf[1][0];

    auto stage = [&](int k0, unsigned char* dst) {
        #pragma unroll
        for (int j = 0; j < 9; ++j)
            async16(srcbase[j] + k0, dst + ldsoff[j]);
    };

    auto compute = [&](const unsigned char* sb) {
        bf16x8 aIn[2], aHid[2];
        #pragma unroll
        for (int mi = 0; mi < 2; ++mi) {
            const int r = wave * 32 + mi * 16 + l16;
            aIn [mi] = *reinterpret_cast<const bf16x8*>(sb + r * 64 + sq * 16);
            aHid[mi] = *reinterpret_cast<const bf16x8*>(sb + 8192 + r * 64 + sq * 16);
        }
        __builtin_amdgcn_s_setprio(1);
        #pragma unroll
        for (int g = 0; g < 5; ++g) {
            #pragma unroll
            for (int ni = 0; ni < 4; ++ni) {
                const int n = ni * 16 + l16;
                const bf16x8 b = *reinterpret_cast<const bf16x8*>(
                    sb + 16384 + g * 4096 + n * 64 + sq * 16);
                #pragma unroll
                for (int mi = 0; mi < 2; ++mi) {
                    const bf16x8 a = (g == 1 || g == 4) ? aHid[mi] : aIn[mi];
                    acc[g][mi][ni] = __builtin_amdgcn_mfma_f32_16x16x32_bf16(a, b, acc[g][mi][ni], 0, 0, 0);
                }
            }
        }
        __builtin_amdgcn_s_setprio(0);
    };

    // ---- pipelined K loop: 32 tiles, 1-deep prefetch, counted vmcnt ----
    // tile t lives in buf[t&1]. Per step: issue stage(t+1) -> wait OWN tile-t
    // loads (vmcnt(9): 9 newer in flight) -> barrier (=> ALL waves' tile-t
    // loads done) -> compute(t) -> barrier (buf[t] may be restaged at t+2).
    stage(0, b0);
    #pragma unroll 1
    for (int i = 0; i < 15; ++i) {
        const int k2 = i * 2 * BK;
        stage(k2 + BK, b1);
        asm volatile("s_waitcnt vmcnt(9)" ::: "memory");
        __builtin_amdgcn_s_barrier(); CFENCE();
        compute(b0); CFENCE();
        __builtin_amdgcn_s_barrier(); CFENCE();

        stage(k2 + 2 * BK, b0);
        asm volatile("s_waitcnt vmcnt(9)" ::: "memory");
        __builtin_amdgcn_s_barrier(); CFENCE();
        compute(b1); CFENCE();
        __builtin_amdgcn_s_barrier(); CFENCE();
    }
    // tiles 30 (in b0) and 31
    stage(31 * BK, b1);
    asm volatile("s_waitcnt vmcnt(9)" ::: "memory");
    __builtin_amdgcn_s_barrier(); CFENCE();
    compute(b0); CFENCE();
    __builtin_amdgcn_s_barrier(); CFENCE();
    asm volatile("s_waitcnt vmcnt(0)" ::: "memory");
    __builtin_amdgcn_s_barrier(); CFENCE();
    compute(b1);

    // Epilogue: C/D layout row = quad*4 + r4, col = l16 per 16x16 tile.
    #pragma unroll
    for (int ni = 0; ni < 4; ++ni) {
        const int gcol = col0 + ni * 16 + l16;
        const float bri = b_ri[gcol], brh = b_rh[gcol], bzi = b_zi[gcol];
        const float bni = b_ni[gcol], bnh = b_nh[gcol];
        #pragma unroll
        for (int mi = 0; mi < 2; ++mi) {
            #pragma unroll
            for (int r4 = 0; r4 < 4; ++r4) {
                const int grow = row0 + wave * 32 + mi * 16 + quad * 4 + r4;
                const float g_ri = acc[0][mi][ni][r4];
                const float g_rh = acc[1][mi][ni][r4];
                const float g_zi = acc[2][mi][ni][r4];
                const float g_ni = acc[3][mi][ni][r4];
                const float g_nh = acc[4][mi][ni][r4];
                const float rh = g_rh + brh;                  // shared by r and z (reference bug kept)
                const float rr = 1.f / (1.f + __expf(-(g_ri + bri + rh)));
                const float zz = 1.f / (1.f + __expf(-(g_zi + bzi + rh)));
                const float nn = tanhf(g_ni + bni + rr * (g_nh + bnh));
                const float h  = hidden[(long long)grow * H + gcol];
                const float o  = (1.f - zz) * nn + zz * h;
                out[(long long)grow * H + gcol]      = o;
                out[BH + (long long)grow * H + gcol] = o;
            }
        }
    }
}

extern "C" void kernel_launch(void* const* d_in, const int* in_sizes, int n_in,
                              void* d_out, int out_size, void* d_ws, size_t ws_size,
                              hipStream_t stream) {
    const float* input  = (const float*)d_in[0];
    const float* hidden = (const float*)d_in[1];
    const float* W_ri = (const float*)d_in[2];
    const float* b_ri = (const float*)d_in[3];
    const float* W_rh = (const float*)d_in[4];
    const float* b_rh = (const float*)d_in[5];
    const float* W_zi = (const float*)d_in[6];
    const float* b_zi = (const float*)d_in[7];
    // d_in[8], d_in[9] = W_z_h, b_z_h: dead per the reference's bug (z uses r_h)
    const float* W_ni = (const float*)d_in[10];
    const float* b_ni = (const float*)d_in[11];
    const float* W_nh = (const float*)d_in[12];
    const float* b_nh = (const float*)d_in[13];
    float* out = (float*)d_out;
    unsigned short* ws = (unsigned short*)d_ws;

    // gate order in ws: 0=r_i 1=r_h 2=z_i 3=n_i 4=n_h
    convert_bf16<<<2048, 256, 0, stream>>>(input, hidden, W_ri, W_rh, W_zi, W_ni, W_nh, ws);

    dim3 grid(1024 / BN, 16384 / BM);  // (16, 128)
    gru_fused<<<grid, 256, 0, stream>>>(ws, hidden, b_ri, b_rh, b_zi, b_ni, b_nh, out);
}